// Round 1
// baseline (73.039 us; speedup 1.0000x reference)
//
#include <hip/hip_runtime.h>
#include <hip/hip_bf16.h>

// Plane2Depth: per input pixel compute (p,q,r,s) = W @ feat[b,:,h,w],
// then write a 4x4 upsampled output block of 1/max((p*u + q*v + r)*s, 0.1).
// Note: the norm in the reference cancels exactly: (p/n*u + q/n*v + r/n)*(s*n)
// == (p*u + q*v + r)*s, epsilon included, so we skip sqrt entirely.

#define IN_H 192
#define IN_W 192
#define NBATCH 16
#define UPF 4
#define OUT_H (IN_H * UPF)
#define OUT_W (IN_W * UPF)

__global__ __launch_bounds__(256) void plane2depth_kernel(
    const float* __restrict__ feat,   // (16, 4, 192, 192)
    const float* __restrict__ Wm,     // (4, 4) row-major: Wm[o*4+i]
    float* __restrict__ out)          // (16, 1, 768, 768)
{
    const int npix = IN_H * IN_W;
    int idx = blockIdx.x * blockDim.x + threadIdx.x;
    if (idx >= NBATCH * npix) return;

    int b  = idx / npix;
    int hw = idx - b * npix;
    int h  = hw / IN_W;
    int w  = hw - h * IN_W;

    // Load the 4 input channels for this pixel (coalesced across lanes).
    const float* f = feat + (size_t)b * 4 * npix + hw;
    float f0 = f[0];
    float f1 = f[npix];
    float f2 = f[2 * npix];
    float f3 = f[3 * npix];

    // W is a uniform address -> scalar loads; 4x4 matvec.
    float p = Wm[0]  * f0 + Wm[1]  * f1 + Wm[2]  * f2 + Wm[3]  * f3;
    float q = Wm[4]  * f0 + Wm[5]  * f1 + Wm[6]  * f2 + Wm[7]  * f3;
    float r = Wm[8]  * f0 + Wm[9]  * f1 + Wm[10] * f2 + Wm[11] * f3;
    float s = Wm[12] * f0 + Wm[13] * f1 + Wm[14] * f2 + Wm[15] * f3;

    // u_j = v_j = (j - 1.5) / 4
    const float uv0 = -0.375f, uv1 = -0.125f, uv2 = 0.125f, uv3 = 0.375f;
    float pu0 = p * uv0, pu1 = p * uv1, pu2 = p * uv2, pu3 = p * uv3;

    float* o = out + (size_t)b * OUT_H * OUT_W + (size_t)(UPF * h) * OUT_W + UPF * w;

    const float vrow[4] = {uv0, uv1, uv2, uv3};
#pragma unroll
    for (int i = 0; i < 4; ++i) {
        float base = q * vrow[i] + r;
        float d0 = (pu0 + base) * s;
        float d1 = (pu1 + base) * s;
        float d2 = (pu2 + base) * s;
        float d3 = (pu3 + base) * s;
        float4 v4;
        v4.x = 1.0f / fmaxf(d0, 0.1f);
        v4.y = 1.0f / fmaxf(d1, 0.1f);
        v4.z = 1.0f / fmaxf(d2, 0.1f);
        v4.w = 1.0f / fmaxf(d3, 0.1f);
        *reinterpret_cast<float4*>(o + (size_t)i * OUT_W) = v4;
    }
}

extern "C" void kernel_launch(void* const* d_in, const int* in_sizes, int n_in,
                              void* d_out, int out_size, void* d_ws, size_t ws_size,
                              hipStream_t stream) {
    const float* feat = (const float*)d_in[0];
    const float* Wm   = (const float*)d_in[1];
    float* out        = (float*)d_out;

    const int total = NBATCH * IN_H * IN_W;      // 589,824 threads
    const int block = 256;
    const int grid  = (total + block - 1) / block;
    plane2depth_kernel<<<grid, block, 0, stream>>>(feat, Wm, out);
}